// Round 13
// baseline (82.137 us; speedup 1.0000x reference)
//
#include <hip/hip_runtime.h>
#include <hip/hip_bf16.h>

#define MM 128      // molecules
#define NA 21       // atoms
#define DD 210      // descriptors
#define DP 224      // padded descriptors
#define TT 4096     // training points
#define NC 64       // t-chunks
#define CHT 64      // t per chunk (== wave width)
#define XPAD 20     // xst LDS row stride

#define QF   0.22360679774997896f   // sqrt(5)/10
#define Q2F  0.05f                  // Q^2
#define K0E  0.016666666666666666f  // 5/(3*SIG^2)
#define INVQ 4.47213595499958f      // 1/Q

// ---- workspace layout (float offsets) ----
#define OFF_TRP  0                        // [TT][DP]
#define OFF_JXP  (OFF_TRP + TT*DP)        // [TT][DP]
#define OFF_TRPT (OFF_JXP + TT*DP)        // [DP][TT]
#define OFF_JXPT (OFF_TRPT + DP*TT)       // [DP][TT]
#define OFF_XSP  (OFF_JXPT + DP*TT)       // [MM][DP]
#define OFF_NT   (OFF_XSP + MM*DP)        // [TT]
#define OFF_CT   (OFF_NT + TT)            // [TT]
#define OFF_NM   (OFF_CT + TT)            // [MM]
#define OFF_S1P  (OFF_NM + MM)            // [NC][MM]
#define OFF_EP   (OFF_S1P + NC*MM)        // [NC][MM]
#define OFF_P1   (OFF_EP + NC*MM)         // [NC][MM][DP]
#define OFF_P2   (OFF_P1 + NC*MM*DP)      // [NC][MM][DP]
#define OFF_FSX  (OFF_P2 + NC*MM*DP)      // [MM][DP]

// ---------- K0: blocks [0,128): 32-t tiles -> trp/jxp + trpT/jxpT + nt/ct
// ----------     blocks [128,256): per-molecule descriptors xs + nm ----------
__global__ __launch_bounds__(256) void k0_prep(
        const float* __restrict__ tr, const float* __restrict__ jx,
        const float* __restrict__ Rs,
        float* __restrict__ trp, float* __restrict__ jxp,
        float* __restrict__ trpT, float* __restrict__ jxpT,
        float* __restrict__ nt, float* __restrict__ ct,
        float* __restrict__ xsp, float* __restrict__ nmg) {
    __shared__ float S1[32][225];
    __shared__ float S2[32][225];
    int b = blockIdx.x, tid = threadIdx.x;

    if (b < 128) {
        int t0 = b * 32;
        for (int i = tid; i < 32 * 224; i += 256) {
            int t = i / 224, d = i - t * 224;
            float v1 = 0.f, v2 = 0.f;
            if (d < DD) { v1 = tr[(t0 + t) * DD + d]; v2 = jx[(t0 + t) * DD + d]; }
            S1[t][d] = v1; S2[t][d] = v2;
            trp[(t0 + t) * DP + d] = v1;
            jxp[(t0 + t) * DP + d] = v2;
        }
        __syncthreads();
        if (tid < 64) {
            int t = tid & 31, h = tid >> 5;
            float sn = 0.f, sc = 0.f;
            int d0 = h * 112;
            for (int d = d0; d < d0 + 112; ++d) {
                float v1 = S1[t][d];
                sn = fmaf(v1, v1, sn);
                sc = fmaf(v1, S2[t][d], sc);
            }
            sn += __shfl_xor(sn, 32);
            sc += __shfl_xor(sc, 32);
            if (h == 0) { nt[t0 + t] = sn; ct[t0 + t] = sc; }
        }
        for (int i = tid; i < 224 * 32; i += 256) {
            int d = i >> 5, t = i & 31;
            trpT[d * TT + t0 + t] = S1[t][d];
            jxpT[d * TT + t0 + t] = S2[t][d];
        }
    } else {
        int m = b - 128;
        float* Rl  = &S1[0][0];
        float* red = &S2[0][0];
        if (tid < NA * 3) Rl[tid] = Rs[m * NA * 3 + tid];
        __syncthreads();
        float v = 0.f;
        if (tid < DP) {
            float x = 0.f;
            if (tid < DD) {
                int d = tid;
                int a = (int)((1.0f + sqrtf(8.0f * (float)d + 1.0f)) * 0.5f);
                while (a * (a - 1) / 2 > d) --a;
                while ((a + 1) * a / 2 <= d) ++a;
                int bb = d - a * (a - 1) / 2;
                float dx = Rl[a * 3 + 0] - Rl[bb * 3 + 0];
                float dy = Rl[a * 3 + 1] - Rl[bb * 3 + 1];
                float dz = Rl[a * 3 + 2] - Rl[bb * 3 + 2];
                x = 1.0f / sqrtf(dx * dx + dy * dy + dz * dz);
            }
            xsp[m * DP + tid] = x;
            v = x * x;
        }
        #pragma unroll
        for (int off = 32; off >= 1; off >>= 1) v += __shfl_xor(v, off);
        if ((tid & 63) == 0) red[tid >> 6] = v;
        __syncthreads();
        if (tid == 0) nmg[m] = red[0] + red[1] + red[2] + red[3];
    }
}

// ---------- K23 v7: phase A (LDS xs, 3-deep) + phase B (LDS W, 4-deep) ----------
#define PA_LOAD(bt, bj, KK) do { \
    _Pragma("unroll") \
    for (int u = 0; u < 8; ++u) { \
        bt[u] = tb[(KK + u) * TT]; \
        bj[u] = jb[(KK + u) * TT]; \
    } } while (0)

#define PA_FMA(bt, bj, KK) do { \
    _Pragma("unroll") \
    for (int u = 0; u < 8; ++u) { \
        float4 a = *(const float4*)&xst[(KK + u) * XPAD + my4]; \
        g1[0] = fmaf(a.x, bt[u], g1[0]); \
        g1[1] = fmaf(a.y, bt[u], g1[1]); \
        g1[2] = fmaf(a.z, bt[u], g1[2]); \
        g1[3] = fmaf(a.w, bt[u], g1[3]); \
        g2[0] = fmaf(a.x, bj[u], g2[0]); \
        g2[1] = fmaf(a.y, bj[u], g2[1]); \
        g2[2] = fmaf(a.z, bj[u], g2[2]); \
        g2[3] = fmaf(a.w, bj[u], g2[3]); \
    } } while (0)

#define PB_LOAD(x1v, x2v, T) do { \
    x1v[0] = *(const float4*)&trp[(t0 + (T)) * DP + d0]; \
    x1v[1] = *(const float4*)&trp[(t0 + (T) + 1) * DP + d0]; \
    x2v[0] = *(const float4*)&jxp[(t0 + (T)) * DP + d0]; \
    x2v[1] = *(const float4*)&jxp[(t0 + (T) + 1) * DP + d0]; } while (0)

#define PB_FMA(x1v, x2v, T) do { \
    _Pragma("unroll") \
    for (int i = 0; i < 4; ++i) { \
        float2 w1p = *(const float2*)&Wl1[my4 + i][(T)]; \
        float2 w2p = *(const float2*)&Wl2[my4 + i][(T)]; \
        a1[i].x = fmaf(w1p.x, x1v[0].x, fmaf(w1p.y, x1v[1].x, a1[i].x)); \
        a1[i].y = fmaf(w1p.x, x1v[0].y, fmaf(w1p.y, x1v[1].y, a1[i].y)); \
        a1[i].z = fmaf(w1p.x, x1v[0].z, fmaf(w1p.y, x1v[1].z, a1[i].z)); \
        a1[i].w = fmaf(w1p.x, x1v[0].w, fmaf(w1p.y, x1v[1].w, a1[i].w)); \
        a2[i].x = fmaf(w2p.x, x2v[0].x, fmaf(w2p.y, x2v[1].x, a2[i].x)); \
        a2[i].y = fmaf(w2p.x, x2v[0].y, fmaf(w2p.y, x2v[1].y, a2[i].y)); \
        a2[i].z = fmaf(w2p.x, x2v[0].z, fmaf(w2p.y, x2v[1].z, a2[i].z)); \
        a2[i].w = fmaf(w2p.x, x2v[0].w, fmaf(w2p.y, x2v[1].w, a2[i].w)); \
    } } while (0)

__global__ __launch_bounds__(256) void k23_fused(
        const float* __restrict__ trp, const float* __restrict__ jxp,
        const float* __restrict__ trpT, const float* __restrict__ jxpT,
        const float* __restrict__ xsp, const float* __restrict__ nt,
        const float* __restrict__ ct, const float* __restrict__ nm,
        float* __restrict__ S1P, float* __restrict__ EP,
        float* __restrict__ P1, float* __restrict__ P2) {
    __shared__ __align__(16) float xst[224 * XPAD];   // [k][m], 17.9 KB
    __shared__ __align__(16) float Wl1[16][CHT];      // 4 KB
    __shared__ __align__(16) float Wl2[16][CHT];      // 4 KB
    int tid = threadIdx.x;
    int c = blockIdx.x, m0 = blockIdx.y * 16;
    int t0 = c * CHT;
    int tx = tid & 63, wq = tid >> 6, my4 = wq * 4;
    int mq = m0 + my4;

    for (int i = tid; i < 16 * 224; i += 256) {
        int m = i / 224, k = i - m * 224;
        xst[k * XPAD + m] = xsp[(m0 + m) * DP + k];
    }
    __syncthreads();

    // ---- phase A: 3-deep slab rotation (slab = 8 k) ----
    float g1[4] = {0.f, 0.f, 0.f, 0.f};
    float g2[4] = {0.f, 0.f, 0.f, 0.f};
    const float* tb = trpT + t0 + tx;
    const float* jb = jxpT + t0 + tx;
    {
        float At[8], Aj[8], Bt[8], Bj[8], Ct[8], Cj[8];
        PA_LOAD(At, Aj, 0);
        PA_LOAD(Bt, Bj, 8);
        for (int k8 = 0; k8 < 176; k8 += 24) {   // k8 = 0,24,...,168
            PA_LOAD(Ct, Cj, k8 + 16); PA_FMA(At, Aj, k8);
            PA_LOAD(At, Aj, k8 + 24); PA_FMA(Bt, Bj, k8 + 8);
            PA_LOAD(Bt, Bj, k8 + 32); PA_FMA(Ct, Cj, k8 + 16);
        }
        PA_LOAD(Ct, Cj, 208); PA_FMA(At, Aj, 192);
        PA_LOAD(At, Aj, 216); PA_FMA(Bt, Bj, 200);
        PA_FMA(Ct, Cj, 208);  PA_FMA(At, Aj, 216);
    }

    // ---- W epilogue -> per-wave LDS rows + s1/E partials ----
    float ntv = nt[t0 + tx], ctv = ct[t0 + tx];
    float s1l[4], el[4];
    #pragma unroll
    for (int i = 0; i < 4; ++i) {
        float nmv = nm[mq + i];
        float d2 = Q2F * (nmv + ntv - 2.f * g1[i]);
        float xd = sqrtf(fmaxf(d2, 0.f));
        float e  = K0E * __expf(-xd);
        float dv = QF * (g2[i] - ctv);
        float w1 = e * dv;
        float w2 = e * (1.f + xd);
        Wl1[my4 + i][tx] = w1;
        Wl2[my4 + i][tx] = w2;
        s1l[i] = w1;
        el[i]  = w2 * dv;
    }
    #pragma unroll
    for (int off = 32; off >= 1; off >>= 1) {
        #pragma unroll
        for (int i = 0; i < 4; ++i) {
            s1l[i] += __shfl_xor(s1l[i], off);
            el[i]  += __shfl_xor(el[i], off);
        }
    }
    if (tx == 0) {
        #pragma unroll
        for (int i = 0; i < 4; ++i) {
            S1P[c * MM + mq + i] = s1l[i];
            EP [c * MM + mq + i] = el[i];
        }
    }
    // no barrier: wave reads only Wl rows it wrote (within-wave LDS ordering)

    // ---- phase B: 4-deep rotation over 2t-steps ----
    int d0 = 4 * (tx < 56 ? tx : 55);
    bool act = (tx < 56);
    float4 a1[4], a2[4];
    #pragma unroll
    for (int i = 0; i < 4; ++i) { a1[i] = {0.f,0.f,0.f,0.f}; a2[i] = {0.f,0.f,0.f,0.f}; }
    {
        float4 A1v[2], A2v[2], B1v[2], B2v[2], C1v[2], C2v[2], D1v[2], D2v[2];
        PB_LOAD(A1v, A2v, 0);
        PB_LOAD(B1v, B2v, 2);
        PB_LOAD(C1v, C2v, 4);
        for (int s = 0; s < 28; s += 4) {        // s = 0,4,...,24 (t = 2s)
            PB_LOAD(D1v, D2v, 2*s + 6);  PB_FMA(A1v, A2v, 2*s);
            PB_LOAD(A1v, A2v, 2*s + 8);  PB_FMA(B1v, B2v, 2*s + 2);
            PB_LOAD(B1v, B2v, 2*s + 10); PB_FMA(C1v, C2v, 2*s + 4);
            PB_LOAD(C1v, C2v, 2*s + 12); PB_FMA(D1v, D2v, 2*s + 6);
        }
        PB_LOAD(D1v, D2v, 62); PB_FMA(A1v, A2v, 56);
        PB_FMA(B1v, B2v, 58);
        PB_FMA(C1v, C2v, 60);
        PB_FMA(D1v, D2v, 62);
    }
    if (act) {
        #pragma unroll
        for (int i = 0; i < 4; ++i) {
            *(float4*)&P1[((size_t)c * MM + mq + i) * DP + d0] = a1[i];
            *(float4*)&P2[((size_t)c * MM + mq + i) * DP + d0] = a2[i];
        }
    }
}

// ---------- K4a: reduce P over NC chunks -> Fs_x; s1/E reduce + energy ----------
__global__ __launch_bounds__(64) void k4_reduce(
        const float* __restrict__ xsp,
        const float* __restrict__ P1, const float* __restrict__ P2,
        const float* __restrict__ S1P, const float* __restrict__ EP,
        float* __restrict__ Fsx, float* __restrict__ out) {
    int m = blockIdx.x, dq = blockIdx.y, tid = threadIdx.x;
    float s = S1P[tid * MM + m];
    float e = EP [tid * MM + m];
    #pragma unroll
    for (int off = 32; off >= 1; off >>= 1) {
        s += __shfl_xor(s, off);
        e += __shfl_xor(e, off);
    }
    if (tid < 56) {
        int d = dq * 56 + tid;
        float pa = 0.f, pb = 0.f;
        #pragma unroll 8
        for (int cc = 0; cc < NC; ++cc) {
            pa += P1[((size_t)cc * MM + m) * DP + d];
            pb += P2[((size_t)cc * MM + m) * DP + d];
        }
        Fsx[m * DP + d] = QF * xsp[m * DP + d] * s - QF * pa - pb;
    }
    if (dq == 0 && tid == 63) out[m] = e * INVQ;
}

// ---------- K4b: force assembly ----------
__global__ __launch_bounds__(64) void k4_forces(
        const float* __restrict__ Rs, const float* __restrict__ Fsx,
        float* __restrict__ out) {
    int m = blockIdx.x, tid = threadIdx.x;
    __shared__ float fxs[DP];
    __shared__ float Rl[64];
    if (tid < NA * 3) Rl[tid] = Rs[m * NA * 3 + tid];
    fxs[tid]       = Fsx[m * DP + tid];
    fxs[tid + 64]  = Fsx[m * DP + tid + 64];
    fxs[tid + 128] = Fsx[m * DP + tid + 128];
    if (tid < 32) fxs[tid + 192] = Fsx[m * DP + tid + 192];
    __syncthreads();
    if (tid < NA * 3) {
        int b = tid / 3, c = tid - b * 3;
        float acc = 0.f;
        #pragma unroll
        for (int a = 0; a < NA; ++a) {
            if (a == b) continue;
            int hi = a > b ? a : b, lo = a > b ? b : a;
            int d = hi * (hi - 1) / 2 + lo;
            float dx = Rl[a * 3 + 0] - Rl[b * 3 + 0];
            float dy = Rl[a * 3 + 1] - Rl[b * 3 + 1];
            float dz = Rl[a * 3 + 2] - Rl[b * 3 + 2];
            float r2 = dx * dx + dy * dy + dz * dz;
            float ir = 1.0f / sqrtf(r2);
            float w = fxs[d] * ir * ir * ir;
            float comp = (c == 0) ? dx : ((c == 1) ? dy : dz);
            acc = fmaf(w, comp, acc);
        }
        out[MM + m * NA * 3 + tid] = acc;
    }
}

extern "C" void kernel_launch(void* const* d_in, const int* in_sizes, int n_in,
                              void* d_out, int out_size, void* d_ws, size_t ws_size,
                              hipStream_t stream) {
    const float* Rs = (const float*)d_in[0];
    const float* tr = (const float*)d_in[1];
    const float* jx = (const float*)d_in[2];
    float* out = (float*)d_out;
    float* ws = (float*)d_ws;

    float* trp  = ws + OFF_TRP;
    float* jxp  = ws + OFF_JXP;
    float* trpT = ws + OFF_TRPT;
    float* jxpT = ws + OFF_JXPT;
    float* xsp  = ws + OFF_XSP;
    float* nt   = ws + OFF_NT;
    float* ct   = ws + OFF_CT;
    float* nm   = ws + OFF_NM;
    float* S1P  = ws + OFF_S1P;
    float* EP   = ws + OFF_EP;
    float* P1   = ws + OFF_P1;
    float* P2   = ws + OFF_P2;
    float* Fsx  = ws + OFF_FSX;

    k0_prep<<<256, 256, 0, stream>>>(tr, jx, Rs, trp, jxp, trpT, jxpT, nt, ct, xsp, nm);
    k23_fused<<<dim3(NC, MM / 16), 256, 0, stream>>>(trp, jxp, trpT, jxpT, xsp, nt, ct, nm, S1P, EP, P1, P2);
    k4_reduce<<<dim3(MM, 4), 64, 0, stream>>>(xsp, P1, P2, S1P, EP, Fsx, out);
    k4_forces<<<MM, 64, 0, stream>>>(Rs, Fsx, out);
}

// Round 14
// 52.499 us; speedup vs baseline: 1.5646x; 1.5646x over previous
//
#include <hip/hip_runtime.h>
#include <hip/hip_bf16.h>

#define MM 128      // molecules
#define NA 21       // atoms
#define DD 210      // descriptors
#define DP 224      // padded descriptors
#define TT 4096     // training points
#define NC 64       // t-chunks
#define CHT 64      // t per chunk (== wave width)
#define XPAD 20     // xst LDS row stride

#define QF   0.22360679774997896f   // sqrt(5)/10
#define Q2F  0.05f                  // Q^2
#define K0E  0.016666666666666666f  // 5/(3*SIG^2)
#define INVQ 4.47213595499958f      // 1/Q

// ---- workspace layout (float offsets) ----
#define OFF_TRP  0                        // [TT][DP]
#define OFF_JXP  (OFF_TRP + TT*DP)        // [TT][DP]
#define OFF_TRPT (OFF_JXP + TT*DP)        // [DP][TT]
#define OFF_JXPT (OFF_TRPT + DP*TT)       // [DP][TT]
#define OFF_XSP  (OFF_JXPT + DP*TT)       // [MM][DP]
#define OFF_NT   (OFF_XSP + MM*DP)        // [TT]
#define OFF_CT   (OFF_NT + TT)            // [TT]
#define OFF_NM   (OFF_CT + TT)            // [MM]
#define OFF_S1P  (OFF_NM + MM)            // [NC][MM]
#define OFF_EP   (OFF_S1P + NC*MM)        // [NC][MM]
#define OFF_P1   (OFF_EP + NC*MM)         // [NC][MM][DP]
#define OFF_P2   (OFF_P1 + NC*MM*DP)      // [NC][MM][DP]

// ---------- K0: blocks [0,256): 16-t tiles -> trp/jxp + trpT/jxpT + nt/ct
// ----------     blocks [256,384): per-molecule descriptors xs + nm ----------
__global__ __launch_bounds__(256) void k0_prep(
        const float* __restrict__ tr, const float* __restrict__ jx,
        const float* __restrict__ Rs,
        float* __restrict__ trp, float* __restrict__ jxp,
        float* __restrict__ trpT, float* __restrict__ jxpT,
        float* __restrict__ nt, float* __restrict__ ct,
        float* __restrict__ xsp, float* __restrict__ nmg) {
    __shared__ float S1[16][225];
    __shared__ float S2[16][225];
    int b = blockIdx.x, tid = threadIdx.x;

    if (b < 256) {
        int t0 = b * 16;
        for (int i = tid; i < 16 * 224; i += 256) {
            int t = i / 224, d = i - t * 224;
            float v1 = 0.f, v2 = 0.f;
            if (d < DD) { v1 = tr[(t0 + t) * DD + d]; v2 = jx[(t0 + t) * DD + d]; }
            S1[t][d] = v1; S2[t][d] = v2;
            trp[(t0 + t) * DP + d] = v1;
            jxp[(t0 + t) * DP + d] = v2;
        }
        __syncthreads();
        if (tid < 64) {   // nt/ct: 4 segs of 56 d per t
            int t = tid & 15, seg = tid >> 4;
            float sn = 0.f, sc = 0.f;
            int d0 = seg * 56;
            for (int d = d0; d < d0 + 56; ++d) {
                float v1 = S1[t][d];
                sn = fmaf(v1, v1, sn);
                sc = fmaf(v1, S2[t][d], sc);
            }
            sn += __shfl_xor(sn, 16); sn += __shfl_xor(sn, 32);
            sc += __shfl_xor(sc, 16); sc += __shfl_xor(sc, 32);
            if (seg == 0) { nt[t0 + t] = sn; ct[t0 + t] = sc; }
        }
        for (int i = tid; i < 224 * 16; i += 256) {
            int d = i >> 4, t = i & 15;
            trpT[d * TT + t0 + t] = S1[t][d];
            jxpT[d * TT + t0 + t] = S2[t][d];
        }
    } else {
        int m = b - 256;
        float* Rl  = &S1[0][0];
        float* red = &S2[0][0];
        if (tid < NA * 3) Rl[tid] = Rs[m * NA * 3 + tid];
        __syncthreads();
        float v = 0.f;
        if (tid < DP) {
            float x = 0.f;
            if (tid < DD) {
                int d = tid;
                int a = (int)((1.0f + sqrtf(8.0f * (float)d + 1.0f)) * 0.5f);
                while (a * (a - 1) / 2 > d) --a;
                while ((a + 1) * a / 2 <= d) ++a;
                int bb = d - a * (a - 1) / 2;
                float dx = Rl[a * 3 + 0] - Rl[bb * 3 + 0];
                float dy = Rl[a * 3 + 1] - Rl[bb * 3 + 1];
                float dz = Rl[a * 3 + 2] - Rl[bb * 3 + 2];
                x = 1.0f / sqrtf(dx * dx + dy * dy + dz * dz);
            }
            xsp[m * DP + tid] = x;
            v = x * x;
        }
        #pragma unroll
        for (int off = 32; off >= 1; off >>= 1) v += __shfl_xor(v, off);
        if ((tid & 63) == 0) red[tid >> 6] = v;
        __syncthreads();
        if (tid == 0) nmg[m] = red[0] + red[1] + red[2] + red[3];
    }
}

// ---------- K23 (r12 proven): phase A (LDS xs, 2-deep) + phase B (LDS W, 2-deep) ----------
#define PA_LOAD(bt, bj, KK) do { \
    _Pragma("unroll") \
    for (int u = 0; u < 8; ++u) { \
        bt[u] = tb[(KK + u) * TT]; \
        bj[u] = jb[(KK + u) * TT]; \
    } } while (0)

#define PA_FMA(bt, bj, KK) do { \
    _Pragma("unroll") \
    for (int u = 0; u < 8; ++u) { \
        float4 a = *(const float4*)&xst[(KK + u) * XPAD + my4]; \
        g1[0] = fmaf(a.x, bt[u], g1[0]); \
        g1[1] = fmaf(a.y, bt[u], g1[1]); \
        g1[2] = fmaf(a.z, bt[u], g1[2]); \
        g1[3] = fmaf(a.w, bt[u], g1[3]); \
        g2[0] = fmaf(a.x, bj[u], g2[0]); \
        g2[1] = fmaf(a.y, bj[u], g2[1]); \
        g2[2] = fmaf(a.z, bj[u], g2[2]); \
        g2[3] = fmaf(a.w, bj[u], g2[3]); \
    } } while (0)

#define PB_LOAD(xa1, xa2, T) do { \
    xa1[0] = *(const float4*)&trp[(t0 + (T)) * DP + d0]; \
    xa1[1] = *(const float4*)&trp[(t0 + (T) + 1) * DP + d0]; \
    xa2[0] = *(const float4*)&jxp[(t0 + (T)) * DP + d0]; \
    xa2[1] = *(const float4*)&jxp[(t0 + (T) + 1) * DP + d0]; } while (0)

#define PB_FMA(xa1, xa2, T) do { \
    _Pragma("unroll") \
    for (int i = 0; i < 4; ++i) { \
        float2 w1p = *(const float2*)&Wl1[my4 + i][(T)]; \
        float2 w2p = *(const float2*)&Wl2[my4 + i][(T)]; \
        a1[i].x = fmaf(w1p.x, xa1[0].x, fmaf(w1p.y, xa1[1].x, a1[i].x)); \
        a1[i].y = fmaf(w1p.x, xa1[0].y, fmaf(w1p.y, xa1[1].y, a1[i].y)); \
        a1[i].z = fmaf(w1p.x, xa1[0].z, fmaf(w1p.y, xa1[1].z, a1[i].z)); \
        a1[i].w = fmaf(w1p.x, xa1[0].w, fmaf(w1p.y, xa1[1].w, a1[i].w)); \
        a2[i].x = fmaf(w2p.x, xa2[0].x, fmaf(w2p.y, xa2[1].x, a2[i].x)); \
        a2[i].y = fmaf(w2p.x, xa2[0].y, fmaf(w2p.y, xa2[1].y, a2[i].y)); \
        a2[i].z = fmaf(w2p.x, xa2[0].z, fmaf(w2p.y, xa2[1].z, a2[i].z)); \
        a2[i].w = fmaf(w2p.x, xa2[0].w, fmaf(w2p.y, xa2[1].w, a2[i].w)); \
    } } while (0)

__global__ __launch_bounds__(256) void k23_fused(
        const float* __restrict__ trp, const float* __restrict__ jxp,
        const float* __restrict__ trpT, const float* __restrict__ jxpT,
        const float* __restrict__ xsp, const float* __restrict__ nt,
        const float* __restrict__ ct, const float* __restrict__ nm,
        float* __restrict__ S1P, float* __restrict__ EP,
        float* __restrict__ P1, float* __restrict__ P2) {
    __shared__ __align__(16) float xst[224 * XPAD];   // [k][m], 17.9 KB
    __shared__ __align__(16) float Wl1[16][CHT];      // 4 KB
    __shared__ __align__(16) float Wl2[16][CHT];      // 4 KB
    int tid = threadIdx.x;
    int c = blockIdx.x, m0 = blockIdx.y * 16;
    int t0 = c * CHT;
    int tx = tid & 63, wq = tid >> 6, my4 = wq * 4;
    int mq = m0 + my4;

    for (int i = tid; i < 16 * 224; i += 256) {
        int m = i / 224, k = i - m * 224;
        xst[k * XPAD + m] = xsp[(m0 + m) * DP + k];
    }
    __syncthreads();

    // ---- phase A: G1/G2 register GEMM (xs via LDS broadcast) ----
    float g1[4] = {0.f, 0.f, 0.f, 0.f};
    float g2[4] = {0.f, 0.f, 0.f, 0.f};
    const float* tb = trpT + t0 + tx;
    const float* jb = jxpT + t0 + tx;
    {
        float p0t[8], p0j[8], p1t[8], p1j[8];
        PA_LOAD(p0t, p0j, 0);
        int k = 0;
        for (; k < DP - 16; k += 16) {
            PA_LOAD(p1t, p1j, k + 8);
            PA_FMA(p0t, p0j, k);
            PA_LOAD(p0t, p0j, k + 16);
            PA_FMA(p1t, p1j, k + 8);
        }
        PA_LOAD(p1t, p1j, DP - 8);
        PA_FMA(p0t, p0j, DP - 16);
        PA_FMA(p1t, p1j, DP - 8);
    }

    // ---- W epilogue -> per-wave LDS rows + s1/E partials ----
    float ntv = nt[t0 + tx], ctv = ct[t0 + tx];
    float s1l[4], el[4];
    #pragma unroll
    for (int i = 0; i < 4; ++i) {
        float nmv = nm[mq + i];
        float d2 = Q2F * (nmv + ntv - 2.f * g1[i]);
        float xd = sqrtf(fmaxf(d2, 0.f));
        float e  = K0E * __expf(-xd);
        float dv = QF * (g2[i] - ctv);
        float w1 = e * dv;
        float w2 = e * (1.f + xd);
        Wl1[my4 + i][tx] = w1;
        Wl2[my4 + i][tx] = w2;
        s1l[i] = w1;
        el[i]  = w2 * dv;
    }
    #pragma unroll
    for (int off = 32; off >= 1; off >>= 1) {
        #pragma unroll
        for (int i = 0; i < 4; ++i) {
            s1l[i] += __shfl_xor(s1l[i], off);
            el[i]  += __shfl_xor(el[i], off);
        }
    }
    if (tx == 0) {
        #pragma unroll
        for (int i = 0; i < 4; ++i) {
            S1P[c * MM + mq + i] = s1l[i];
            EP [c * MM + mq + i] = el[i];
        }
    }
    // no barrier: wave reads only Wl rows it wrote (within-wave LDS ordering)

    // ---- phase B: A-partials; W via uniform LDS reads, x via float4 ----
    int d0 = 4 * (tx < 56 ? tx : 55);
    bool act = (tx < 56);
    float4 a1[4], a2[4];
    #pragma unroll
    for (int i = 0; i < 4; ++i) { a1[i] = {0.f,0.f,0.f,0.f}; a2[i] = {0.f,0.f,0.f,0.f}; }
    {
        float4 xa1[2], xa2[2], xb1[2], xb2[2];
        PB_LOAD(xa1, xa2, 0);
        int g = 0;
        for (; g < 30; g += 2) {
            PB_LOAD(xb1, xb2, (g + 1) * 2);
            PB_FMA(xa1, xa2, g * 2);
            PB_LOAD(xa1, xa2, (g + 2) * 2);
            PB_FMA(xb1, xb2, (g + 1) * 2);
        }
        PB_LOAD(xb1, xb2, 62);
        PB_FMA(xa1, xa2, 60);
        PB_FMA(xb1, xb2, 62);
    }
    if (act) {
        #pragma unroll
        for (int i = 0; i < 4; ++i) {
            *(float4*)&P1[((size_t)c * MM + mq + i) * DP + d0] = a1[i];
            *(float4*)&P2[((size_t)c * MM + mq + i) * DP + d0] = a2[i];
        }
    }
}

// ---------- K4: 1024-thread P-reduce (4-way chunk split) + forces + energy ----------
__global__ __launch_bounds__(1024) void k4_final(
        const float* __restrict__ Rs, const float* __restrict__ xsp,
        const float* __restrict__ P1, const float* __restrict__ P2,
        const float* __restrict__ S1P, const float* __restrict__ EP,
        float* __restrict__ out) {
    int m = blockIdx.x, tid = threadIdx.x;
    int q = tid >> 8, r = tid & 255;     // q: chunk quarter, r: descriptor
    __shared__ float fred1[4][256];
    __shared__ float fred2[4][256];
    __shared__ float fxs[DD];
    __shared__ float Rl[64];
    __shared__ float sE[2];
    if (tid < NA * 3) Rl[tid] = Rs[m * NA * 3 + tid];
    if (r < DD) {
        float pa = 0.f, pb = 0.f;
        #pragma unroll 8
        for (int cc = q * 16; cc < q * 16 + 16; ++cc) {
            pa += P1[((size_t)cc * MM + m) * DP + r];
            pb += P2[((size_t)cc * MM + m) * DP + r];
        }
        fred1[q][r] = pa;
        fred2[q][r] = pb;
    }
    if (tid < 64) {      // s1/E reduce over NC=64 chunks
        float s = S1P[tid * MM + m];
        float e = EP [tid * MM + m];
        #pragma unroll
        for (int off = 32; off >= 1; off >>= 1) {
            s += __shfl_xor(s, off);
            e += __shfl_xor(e, off);
        }
        if (tid == 0) { sE[0] = s; sE[1] = e; }
    }
    __syncthreads();
    if (tid < DD) {
        float pa = fred1[0][tid] + fred1[1][tid] + fred1[2][tid] + fred1[3][tid];
        float pb = fred2[0][tid] + fred2[1][tid] + fred2[2][tid] + fred2[3][tid];
        fxs[tid] = QF * xsp[m * DP + tid] * sE[0] - QF * pa - pb;
    }
    __syncthreads();
    if (tid < NA * 3) {
        int b = tid / 3, c = tid - b * 3;
        float acc = 0.f;
        #pragma unroll
        for (int a = 0; a < NA; ++a) {
            if (a == b) continue;
            int hi = a > b ? a : b, lo = a > b ? b : a;
            int d = hi * (hi - 1) / 2 + lo;
            float dx = Rl[a * 3 + 0] - Rl[b * 3 + 0];
            float dy = Rl[a * 3 + 1] - Rl[b * 3 + 1];
            float dz = Rl[a * 3 + 2] - Rl[b * 3 + 2];
            float r2 = dx * dx + dy * dy + dz * dz;
            float ir = 1.0f / sqrtf(r2);
            float w = fxs[d] * ir * ir * ir;
            float comp = (c == 0) ? dx : ((c == 1) ? dy : dz);
            acc = fmaf(w, comp, acc);
        }
        out[MM + m * NA * 3 + tid] = acc;
    }
    if (tid == 0) out[m] = sE[1] * INVQ;
}

extern "C" void kernel_launch(void* const* d_in, const int* in_sizes, int n_in,
                              void* d_out, int out_size, void* d_ws, size_t ws_size,
                              hipStream_t stream) {
    const float* Rs = (const float*)d_in[0];
    const float* tr = (const float*)d_in[1];
    const float* jx = (const float*)d_in[2];
    float* out = (float*)d_out;
    float* ws = (float*)d_ws;

    float* trp  = ws + OFF_TRP;
    float* jxp  = ws + OFF_JXP;
    float* trpT = ws + OFF_TRPT;
    float* jxpT = ws + OFF_JXPT;
    float* xsp  = ws + OFF_XSP;
    float* nt   = ws + OFF_NT;
    float* ct   = ws + OFF_CT;
    float* nm   = ws + OFF_NM;
    float* S1P  = ws + OFF_S1P;
    float* EP   = ws + OFF_EP;
    float* P1   = ws + OFF_P1;
    float* P2   = ws + OFF_P2;

    k0_prep<<<384, 256, 0, stream>>>(tr, jx, Rs, trp, jxp, trpT, jxpT, nt, ct, xsp, nm);
    k23_fused<<<dim3(NC, MM / 16), 256, 0, stream>>>(trp, jxp, trpT, jxpT, xsp, nt, ct, nm, S1P, EP, P1, P2);
    k4_final<<<MM, 1024, 0, stream>>>(Rs, xsp, P1, P2, S1P, EP, out);
}